// Round 5
// baseline (992.278 us; speedup 1.0000x reference)
//
#include <hip/hip_runtime.h>

#define BATCH  32
#define DIM    3072
#define NTRAIN 100000
#define WROW   100352        /* wbuf padded row (mult of 16) */
#define SEGJ   12544         /* WROW / 8 */
#define SCH    98            /* j-chunks in PV pass */
#define JPC    1024          /* j per chunk */
#define DSPL   8             /* d-splits in PV pass (384 d each) */
#define NTILE  3             /* 32-col tiles per wave (3*32 = 96 d) */

typedef __bf16 bf16x8 __attribute__((ext_vector_type(8)));
typedef float  f32x16 __attribute__((ext_vector_type(16)));
typedef unsigned short u16;
typedef unsigned int   u32;

union F8 { u16 us[8]; uint4 u4; bf16x8 bf; };

__device__ __forceinline__ u16   bft(float f){ return (u16)(__float_as_uint(f) >> 16); }
__device__ __forceinline__ float bfh(float f){ return __uint_as_float(__float_as_uint(f) & 0xFFFF0000u); }
__device__ __forceinline__ float bfv(u16 h)  { return __uint_as_float(((u32)h) << 16); }

// ---------------- K0: split x into bf16 hi/lo ----------------
__global__ __launch_bounds__(256) void k0_split_x(
        const float* __restrict__ x, u16* __restrict__ xh, u16* __restrict__ xl) {
    int i = blockIdx.x * 256 + threadIdx.x;
    if (i >= BATCH * DIM) return;
    float f = x[i];
    xh[i] = bft(f);
    xl[i] = bft(f - bfh(f));
}

// ---------------- K1v2: logits via LDS-staged, coalesced train reads ----------------
// Block: 32 j-rows, 256 thr (4 waves). 12 chunks of [32 rows][256 k] f32 in LDS
// (32 KB, XOR-swizzled via pre-permuted global source). Waves split k in quarters;
// cross-wave acc+tsq reduce at the end. T14: chunk c+1 loads issued before compute(c).
__global__ __launch_bounds__(256, 4) void k1_logits_v2(
        const float* __restrict__ train,
        const u16* __restrict__ xh, const u16* __restrict__ xl,
        const float* __restrict__ alphas, const int* __restrict__ tptr,
        float* __restrict__ logits) {
    __shared__ __align__(16) char smem[32768];
    const int tid  = threadIdx.x;
    const int lane = tid & 63;
    const int w    = tid >> 6;
    const int l31  = lane & 31;
    const int g    = lane >> 5;
    const int jt0  = blockIdx.x * 32;

    const float ab = alphas[tptr[0]];
    const float s  = sqrtf(ab);
    const float om = 1.0f - ab;
    const float c1 = s / om;
    const float c2 = ab / (2.0f * om);

    // staging maps (constant across chunks): round i stages row i*4+w,
    // lane covers 16 B at swizzled k-slot; LDS dest linear.
    u32 dsto[8]; const char* sbase[8];
#pragma unroll
    for (int i = 0; i < 8; ++i) {
        int row = i * 4 + w;
        dsto[i]  = (u32)(row * 1024 + lane * 16);
        u32 soff = ((u32)(lane * 16)) ^ (((u32)(row & 15)) << 4);
        sbase[i] = (const char*)train + (size_t)(jt0 + row) * (DIM * 4) + soff;
    }

    const u16* xhr = xh + (size_t)l31 * DIM;
    const u16* xlr = xl + (size_t)l31 * DIM;
    const u32 sw = ((u32)(l31 & 15)) << 4;

    f32x16 acc;
#pragma unroll
    for (int r = 0; r < 16; ++r) acc[r] = 0.0f;
    float tsqp = 0.0f;

    float4 stg[8];
#pragma unroll
    for (int i = 0; i < 8; ++i) stg[i] = *(const float4*)(sbase[i]);   // chunk 0

    for (int c = 0; c < 12; ++c) {
        __syncthreads();                       // readers of chunk c-1 done
#pragma unroll
        for (int i = 0; i < 8; ++i) *(float4*)(smem + dsto[i]) = stg[i];
        __syncthreads();                       // staged data visible
        if (c < 11) {                          // issue next chunk early (regs survive barriers)
#pragma unroll
            for (int i = 0; i < 8; ++i)
                stg[i] = *(const float4*)(sbase[i] + (c + 1) * 1024);
        }
        const int kqb = w * 256;               // wave's k-quarter byte base in row
#pragma unroll
        for (int s4 = 0; s4 < 4; ++s4) {
            const u32 kb0 = (u32)(kqb + s4 * 64 + g * 32);
            const float4 f0 = *(const float4*)(smem + (u32)l31 * 1024u + (kb0 ^ sw));
            const float4 f1 = *(const float4*)(smem + (u32)l31 * 1024u + ((kb0 + 16) ^ sw));
            float fv[8] = {f0.x, f0.y, f0.z, f0.w, f1.x, f1.y, f1.z, f1.w};
            F8 bh, bl;
#pragma unroll
            for (int e = 0; e < 8; ++e) {
                float f = fv[e];
                bh.us[e] = bft(f);
                bl.us[e] = bft(f - bfh(f));
                tsqp = fmaf(f, f, tsqp);
            }
            const int kglob = c * 256 + w * 64 + s4 * 16 + g * 8;
            F8 ah, al;
            ah.u4 = *(const uint4*)(xhr + kglob);
            al.u4 = *(const uint4*)(xlr + kglob);
            acc = __builtin_amdgcn_mfma_f32_32x32x16_bf16(ah.bf, bh.bf, acc, 0, 0, 0);
            acc = __builtin_amdgcn_mfma_f32_32x32x16_bf16(al.bf, bh.bf, acc, 0, 0, 0);
            acc = __builtin_amdgcn_mfma_f32_32x32x16_bf16(ah.bf, bl.bf, acc, 0, 0, 0);
        }
    }

    // ---- cross-wave reduce (acc over k-quarters) + tsq, then logits write ----
    tsqp += __shfl_xor(tsqp, 32);              // combine g-halves: wave-quarter sum, row l31
    __syncthreads();                           // all compute done; smem reusable
    float* red = (float*)smem;
    if (w > 0) {
        float* dp = red + ((w - 1) * 64 + lane) * 16;
#pragma unroll
        for (int r = 0; r < 16; ++r) dp[r] = acc[r];
    }
    if (g == 0) red[3072 + w * 32 + l31] = tsqp;
    __syncthreads();
    if (w == 0) {
#pragma unroll
        for (int q = 0; q < 3; ++q) {
            const float* sp = red + (q * 64 + lane) * 16;
#pragma unroll
            for (int r = 0; r < 16; ++r) acc[r] += sp[r];
        }
        const float tsq = red[3072 + l31] + red[3072 + 32 + l31]
                        + red[3072 + 64 + l31] + red[3072 + 96 + l31];
#pragma unroll
        for (int r = 0; r < 16; ++r) {
            int brow = (r & 3) + 8 * (r >> 2) + 4 * g;
            logits[(size_t)brow * NTRAIN + jt0 + l31] = c1 * acc[r] - c2 * tsq;
        }
    }
}

// ---------------- K2a: row max ----------------
__global__ __launch_bounds__(1024) void k2a_rowmax(
        const float* __restrict__ logits, float* __restrict__ m) {
    int b = blockIdx.x;
    const float* row = logits + (size_t)b * NTRAIN;
    float mx = -3.0e38f;
    for (int i = threadIdx.x; i < NTRAIN; i += 1024) mx = fmaxf(mx, row[i]);
    __shared__ float red[1024];
    red[threadIdx.x] = mx;
    __syncthreads();
    for (int off = 512; off > 0; off >>= 1) {
        if (threadIdx.x < (unsigned)off)
            red[threadIdx.x] = fmaxf(red[threadIdx.x], red[threadIdx.x + off]);
        __syncthreads();
    }
    if (threadIdx.x == 0) m[b] = red[0];
}

// ---------------- K2b: weights = bf16(exp(logit - m)), padded; per-seg sums ----------------
__global__ __launch_bounds__(256) void k2b_expw(
        const float* __restrict__ logits, const float* __restrict__ m,
        u16* __restrict__ wbuf, float* __restrict__ lsum) {
    int blk = blockIdx.x;            // 256 = 32 b x 8 seg
    int b   = blk & 31;
    int seg = blk >> 5;
    float mb = m[b];
    int j0 = seg * SEGJ;
    float ls = 0.0f;
    for (int j = j0 + threadIdx.x; j < j0 + SEGJ; j += 256) {
        u16 wv = 0;
        if (j < NTRAIN) {
            float wf = __expf(logits[(size_t)b * NTRAIN + j] - mb);
            wv = bft(wf);
            ls += bfv(wv);           // denominator = sum of the weights PV actually uses
        }
        wbuf[(size_t)b * WROW + j] = wv;
    }
    __shared__ float red[256];
    red[threadIdx.x] = ls;
    __syncthreads();
    for (int off = 128; off > 0; off >>= 1) {
        if (threadIdx.x < (unsigned)off) red[threadIdx.x] += red[threadIdx.x + off];
        __syncthreads();
    }
    if (threadIdx.x == 0) lsum[seg * 32 + b] = red[0];
}

// ---------------- K3: PV pass — one coalesced train stream, no exp, no barriers ----------------
__global__ __launch_bounds__(256) void k3_pv(
        const float* __restrict__ train, const u16* __restrict__ wbuf,
        float* __restrict__ partial) {   // [SCH][BATCH][DIM]
    const int lane = threadIdx.x & 63;
    const int w    = threadIdx.x >> 6;
    const int l31  = lane & 31;
    const int g    = lane >> 5;
    const int ds   = blockIdx.x & (DSPL - 1);
    const int sc   = blockIdx.x / DSPL;
    const int dbase = ds * (DIM / DSPL) + w * (NTILE * 32);

    const u16* wrow = wbuf + (size_t)l31 * WROW;

    f32x16 acc[NTILE];
#pragma unroll
    for (int t = 0; t < NTILE; ++t)
#pragma unroll
        for (int r = 0; r < 16; ++r) acc[t][r] = 0.0f;

    const int jb0 = sc * JPC;

    if (sc < SCH - 1) {
        for (int ks = 0; ks < JPC / 16; ++ks) {
            const int jb = jb0 + ks * 16 + 8 * g;
            F8 af;
            af.u4 = *(const uint4*)(wrow + jb);
            const float* rp = train + (size_t)jb * DIM + dbase + l31;
            F8 bf0, bf1, bf2;
#pragma unroll
            for (int e = 0; e < 8; ++e) {
                const float* q = rp + e * DIM;
                bf0.us[e] = bft(q[0]);
                bf1.us[e] = bft(q[32]);
                bf2.us[e] = bft(q[64]);
            }
            acc[0] = __builtin_amdgcn_mfma_f32_32x32x16_bf16(af.bf, bf0.bf, acc[0], 0, 0, 0);
            acc[1] = __builtin_amdgcn_mfma_f32_32x32x16_bf16(af.bf, bf1.bf, acc[1], 0, 0, 0);
            acc[2] = __builtin_amdgcn_mfma_f32_32x32x16_bf16(af.bf, bf2.bf, acc[2], 0, 0, 0);
        }
    } else {
        for (int ks = 0; ks < JPC / 16; ++ks) {
            const int jb = jb0 + ks * 16 + 8 * g;
            F8 af;
            af.u4 = *(const uint4*)(wrow + jb);   // zeros beyond NTRAIN
            F8 bf0, bf1, bf2;
#pragma unroll
            for (int e = 0; e < 8; ++e) {
                int row = jb + e;
                row = row < NTRAIN ? row : (NTRAIN - 1);   // clamp: weight is 0 there
                const float* q = train + (size_t)row * DIM + dbase + l31;
                bf0.us[e] = bft(q[0]);
                bf1.us[e] = bft(q[32]);
                bf2.us[e] = bft(q[64]);
            }
            acc[0] = __builtin_amdgcn_mfma_f32_32x32x16_bf16(af.bf, bf0.bf, acc[0], 0, 0, 0);
            acc[1] = __builtin_amdgcn_mfma_f32_32x32x16_bf16(af.bf, bf1.bf, acc[1], 0, 0, 0);
            acc[2] = __builtin_amdgcn_mfma_f32_32x32x16_bf16(af.bf, bf2.bf, acc[2], 0, 0, 0);
        }
    }

#pragma unroll
    for (int t = 0; t < NTILE; ++t)
#pragma unroll
        for (int r = 0; r < 16; ++r) {
            int brow = (r & 3) + 8 * (r >> 2) + 4 * g;
            partial[((size_t)sc * BATCH + brow) * DIM + dbase + t * 32 + l31] = acc[t][r];
        }
}

// ---------------- K4: merge partials, scale, output ----------------
__global__ __launch_bounds__(256) void k4_final(
        const float* __restrict__ x, const float* __restrict__ partial,
        const float* __restrict__ lsum,
        const float* __restrict__ alphas, const int* __restrict__ tptr,
        float* __restrict__ out) {
    int i = blockIdx.x * 256 + threadIdx.x;
    if (i >= BATCH * DIM) return;
    int b = i / DIM;
    float ab  = alphas[tptr[0]];
    float s   = sqrtf(ab);
    float om  = 1.0f - ab;
    float inv = 1.0f / sqrtf(om);
    float L = 0.0f;
#pragma unroll
    for (int s2 = 0; s2 < 8; ++s2) L += lsum[s2 * 32 + b];
    float wsum = 0.0f;
#pragma unroll 4
    for (int c = 0; c < SCH; ++c)
        wsum += partial[(size_t)c * (BATCH * DIM) + i];
    out[i] = inv * x[i] - s * inv * (wsum / L);
}

extern "C" void kernel_launch(void* const* d_in, const int* in_sizes, int n_in,
                              void* d_out, int out_size, void* d_ws, size_t ws_size,
                              hipStream_t stream) {
    const float* x      = (const float*)d_in[0];
    const float* train  = (const float*)d_in[1];
    const float* alphas = (const float*)d_in[2];
    const int*   tptr   = (const int*)d_in[3];
    float* out = (float*)d_out;

    char* ws = (char*)d_ws;
    float* logits  = (float*)ws;                               // 12,800,000 B
    float* partial = (float*)(ws + 12800000);                  // 38,535,168 B
    u16*   wbuf    = (u16*)(ws + 12800000 + 38535168);         //  6,422,528 B
    float* m_arr   = (float*)(ws + 57757696);                  //        128 B
    float* lsum    = (float*)(ws + 57757824);                  //       1024 B
    u16*   xh      = (u16*)(ws + 57758848);                    //    196,608 B
    u16*   xl      = (u16*)(ws + 57955456);                    //    196,608 B

    k0_split_x<<<(BATCH * DIM + 255) / 256, 256, 0, stream>>>(x, xh, xl);
    k1_logits_v2<<<NTRAIN / 32, 256, 0, stream>>>(train, xh, xl, alphas, tptr, logits);
    k2a_rowmax<<<BATCH, 1024, 0, stream>>>(logits, m_arr);
    k2b_expw<<<256, 256, 0, stream>>>(logits, m_arr, wbuf, lsum);
    k3_pv<<<DSPL * SCH, 256, 0, stream>>>(train, wbuf, partial);
    k4_final<<<(BATCH * DIM + 255) / 256, 256, 0, stream>>>(x, partial, lsum, alphas, tptr, out);
}

// Round 6
// 628.131 us; speedup vs baseline: 1.5797x; 1.5797x over previous
//
#include <hip/hip_runtime.h>

#define BATCH  32
#define DIM    3072
#define NTRAIN 100000
#define WROW   100352        /* wbuf padded row (mult of 16) */
#define SEGJ   12544         /* WROW / 8 */
#define SCH    98            /* j-chunks in PV pass */
#define JPC    1024          /* j per chunk */
#define DSPL   8             /* d-splits in PV pass (384 d each) */
#define NTILE  3             /* 32-col tiles per wave (3*32 = 96 d) */

/* k1 v3 */
#define KCH    256           /* k per chunk */
#define NCH    12            /* DIM / KCH */
#define ROWB   1040          /* 1024 B data + 16 B pad (16-aligned, 4-way-conflict reads) */
#define BUFB   (32 * ROWB)   /* 33280 B per buffer */

typedef __bf16 bf16x8 __attribute__((ext_vector_type(8)));
typedef float  f32x16 __attribute__((ext_vector_type(16)));
typedef unsigned short u16;
typedef unsigned int   u32;

union F8 { u16 us[8]; u32 ui[4]; uint4 u4; bf16x8 bf; };

__device__ __forceinline__ u16   bft(float f){ return (u16)(__float_as_uint(f) >> 16); }
__device__ __forceinline__ float bfh(float f){ return __uint_as_float(__float_as_uint(f) & 0xFFFF0000u); }
__device__ __forceinline__ float bfv(u16 h)  { return __uint_as_float(((u32)h) << 16); }

// ---------------- K0: split x into bf16 hi/lo ----------------
__global__ __launch_bounds__(256) void k0_split_x(
        const float* __restrict__ x, u16* __restrict__ xh, u16* __restrict__ xl) {
    int i = blockIdx.x * 256 + threadIdx.x;
    if (i >= BATCH * DIM) return;
    float f = x[i];
    xh[i] = bft(f);
    xl[i] = bft(f - bfh(f));
}

// ---------------- K1v3: logits via global_load_lds-staged coalesced train ----------------
// Block: 32 j-rows, 4 waves splitting k in quarters. Double-buffered LDS
// (2 x 32 rows x 1040 B). Stage = 8 global_load_lds width-16 per wave (one
// full row per instruction, zero staging registers). One barrier per chunk.
__global__ __launch_bounds__(256) void k1_logits_v3(
        const float* __restrict__ train,
        const u16* __restrict__ xh, const u16* __restrict__ xl,
        const float* __restrict__ alphas, const int* __restrict__ tptr,
        float* __restrict__ logits) {
    __shared__ __align__(16) char smem[2 * BUFB];
    const int tid  = threadIdx.x;
    const int lane = tid & 63;
    const int w    = tid >> 6;
    const int l31  = lane & 31;
    const int g    = lane >> 5;
    const int jt0  = blockIdx.x * 32;

    const float ab = alphas[tptr[0]];
    const float s  = sqrtf(ab);
    const float om = 1.0f - ab;
    const float c1 = s / om;
    const float c2 = ab / (2.0f * om);

    const u16* xhr = xh + (size_t)l31 * DIM;
    const u16* xlr = xl + (size_t)l31 * DIM;
    const char* gblk = (const char*)train + (size_t)jt0 * (DIM * 4);

    f32x16 acc;
#pragma unroll
    for (int r = 0; r < 16; ++r) acc[r] = 0.0f;
    float tsqp = 0.0f;

    // wave w stages rows w*8 .. w*8+7 of chunk c into buffer `buf`
    auto stage = [&](int buf, int c) {
#pragma unroll
        for (int i = 0; i < 8; ++i) {
            const int r = w * 8 + i;
            const char* src = gblk + (size_t)r * (DIM * 4) + c * (KCH * 4) + lane * 16;
            char* dst = smem + buf * BUFB + r * ROWB;
            __builtin_amdgcn_global_load_lds(
                (const __attribute__((address_space(1))) unsigned int*)src,
                (__attribute__((address_space(3))) unsigned int*)dst,
                16, 0, 0);
        }
    };

    stage(0, 0);
    __syncthreads();                       // drains vmcnt -> chunk 0 visible

    int cur = 0;
    for (int c = 0; c < NCH; ++c) {
        if (c + 1 < NCH) stage(cur ^ 1, c + 1);   // in flight across compute

        F8 ah[4], al[4];
#pragma unroll
        for (int s4 = 0; s4 < 4; ++s4) {
            const int kglob = c * KCH + w * 64 + s4 * 16 + g * 8;
            ah[s4].u4 = *(const uint4*)(xhr + kglob);
            al[s4].u4 = *(const uint4*)(xlr + kglob);
        }

        const char* lb = smem + cur * BUFB + l31 * ROWB;
#pragma unroll
        for (int s4 = 0; s4 < 4; ++s4) {
            const u32 kb0 = (u32)(w * 256 + s4 * 64 + g * 32);
            const float4 f0 = *(const float4*)(lb + kb0);
            const float4 f1 = *(const float4*)(lb + kb0 + 16);
            float fv[8] = {f0.x, f0.y, f0.z, f0.w, f1.x, f1.y, f1.z, f1.w};
            F8 bh, bl;
#pragma unroll
            for (int e = 0; e < 8; ++e) {
                float f = fv[e];
                bh.us[e] = bft(f);
                bl.us[e] = bft(f - bfh(f));
                tsqp = fmaf(f, f, tsqp);
            }
            acc = __builtin_amdgcn_mfma_f32_32x32x16_bf16(ah[s4].bf, bh.bf, acc, 0, 0, 0);
            acc = __builtin_amdgcn_mfma_f32_32x32x16_bf16(al[s4].bf, bh.bf, acc, 0, 0, 0);
            acc = __builtin_amdgcn_mfma_f32_32x32x16_bf16(ah[s4].bf, bl.bf, acc, 0, 0, 0);
        }
        __syncthreads();                   // readers done + next stage landed
        cur ^= 1;
    }

    // ---- cross-wave reduce (acc over k-quarters) + tsq, then logits write ----
    tsqp += __shfl_xor(tsqp, 32);          // merge g-halves: per (w, row l31)
    float* red = (float*)smem;
    if (w > 0) {
        float* dp = red + ((w - 1) * 64 + lane) * 16;
#pragma unroll
        for (int r = 0; r < 16; ++r) dp[r] = acc[r];
    }
    if (g == 0) red[3072 + w * 32 + l31] = tsqp;
    __syncthreads();
    if (w == 0) {
#pragma unroll
        for (int q = 0; q < 3; ++q) {
            const float* sp = red + (q * 64 + lane) * 16;
#pragma unroll
            for (int r = 0; r < 16; ++r) acc[r] += sp[r];
        }
        const float tsq = red[3072 + l31] + red[3072 + 32 + l31]
                        + red[3072 + 64 + l31] + red[3072 + 96 + l31];
#pragma unroll
        for (int r = 0; r < 16; ++r) {
            int brow = (r & 3) + 8 * (r >> 2) + 4 * g;
            logits[(size_t)brow * NTRAIN + jt0 + l31] = c1 * acc[r] - c2 * tsq;
        }
    }
}

// ---------------- K2a: row max ----------------
__global__ __launch_bounds__(1024) void k2a_rowmax(
        const float* __restrict__ logits, float* __restrict__ m) {
    int b = blockIdx.x;
    const float* row = logits + (size_t)b * NTRAIN;
    float mx = -3.0e38f;
    for (int i = threadIdx.x; i < NTRAIN; i += 1024) mx = fmaxf(mx, row[i]);
    __shared__ float red[1024];
    red[threadIdx.x] = mx;
    __syncthreads();
    for (int off = 512; off > 0; off >>= 1) {
        if (threadIdx.x < (unsigned)off)
            red[threadIdx.x] = fmaxf(red[threadIdx.x], red[threadIdx.x + off]);
        __syncthreads();
    }
    if (threadIdx.x == 0) m[b] = red[0];
}

// ---------------- K2b: weights = bf16(exp(logit - m)), padded; per-seg sums ----------------
__global__ __launch_bounds__(256) void k2b_expw(
        const float* __restrict__ logits, const float* __restrict__ m,
        u16* __restrict__ wbuf, float* __restrict__ lsum) {
    int blk = blockIdx.x;            // 256 = 32 b x 8 seg
    int b   = blk & 31;
    int seg = blk >> 5;
    float mb = m[b];
    int j0 = seg * SEGJ;
    float ls = 0.0f;
    for (int j = j0 + threadIdx.x; j < j0 + SEGJ; j += 256) {
        u16 wv = 0;
        if (j < NTRAIN) {
            float wf = __expf(logits[(size_t)b * NTRAIN + j] - mb);
            wv = bft(wf);
            ls += bfv(wv);           // denominator = sum of the weights PV actually uses
        }
        wbuf[(size_t)b * WROW + j] = wv;
    }
    __shared__ float red[256];
    red[threadIdx.x] = ls;
    __syncthreads();
    for (int off = 128; off > 0; off >>= 1) {
        if (threadIdx.x < (unsigned)off) red[threadIdx.x] += red[threadIdx.x + off];
        __syncthreads();
    }
    if (threadIdx.x == 0) lsum[seg * 32 + b] = red[0];
}

// ---------------- K3: PV pass — one coalesced train stream, no exp, no barriers ----------------
__global__ __launch_bounds__(256) void k3_pv(
        const float* __restrict__ train, const u16* __restrict__ wbuf,
        float* __restrict__ partial) {   // [SCH][BATCH][DIM]
    const int lane = threadIdx.x & 63;
    const int w    = threadIdx.x >> 6;
    const int l31  = lane & 31;
    const int g    = lane >> 5;
    const int ds   = blockIdx.x & (DSPL - 1);
    const int sc   = blockIdx.x / DSPL;
    const int dbase = ds * (DIM / DSPL) + w * (NTILE * 32);

    const u16* wrow = wbuf + (size_t)l31 * WROW;

    f32x16 acc[NTILE];
#pragma unroll
    for (int t = 0; t < NTILE; ++t)
#pragma unroll
        for (int r = 0; r < 16; ++r) acc[t][r] = 0.0f;

    const int jb0 = sc * JPC;

    if (sc < SCH - 1) {
        for (int ks = 0; ks < JPC / 16; ++ks) {
            const int jb = jb0 + ks * 16 + 8 * g;
            F8 af;
            af.u4 = *(const uint4*)(wrow + jb);
            const float* rp = train + (size_t)jb * DIM + dbase + l31;
            F8 bf0, bf1, bf2;
#pragma unroll
            for (int e = 0; e < 8; ++e) {
                const float* q = rp + e * DIM;
                bf0.us[e] = bft(q[0]);
                bf1.us[e] = bft(q[32]);
                bf2.us[e] = bft(q[64]);
            }
            acc[0] = __builtin_amdgcn_mfma_f32_32x32x16_bf16(af.bf, bf0.bf, acc[0], 0, 0, 0);
            acc[1] = __builtin_amdgcn_mfma_f32_32x32x16_bf16(af.bf, bf1.bf, acc[1], 0, 0, 0);
            acc[2] = __builtin_amdgcn_mfma_f32_32x32x16_bf16(af.bf, bf2.bf, acc[2], 0, 0, 0);
        }
    } else {
        for (int ks = 0; ks < JPC / 16; ++ks) {
            const int jb = jb0 + ks * 16 + 8 * g;
            F8 af;
            af.u4 = *(const uint4*)(wrow + jb);   // zeros beyond NTRAIN
            F8 bf0, bf1, bf2;
#pragma unroll
            for (int e = 0; e < 8; ++e) {
                int row = jb + e;
                row = row < NTRAIN ? row : (NTRAIN - 1);   // clamp: weight is 0 there
                const float* q = train + (size_t)row * DIM + dbase + l31;
                bf0.us[e] = bft(q[0]);
                bf1.us[e] = bft(q[32]);
                bf2.us[e] = bft(q[64]);
            }
            acc[0] = __builtin_amdgcn_mfma_f32_32x32x16_bf16(af.bf, bf0.bf, acc[0], 0, 0, 0);
            acc[1] = __builtin_amdgcn_mfma_f32_32x32x16_bf16(af.bf, bf1.bf, acc[1], 0, 0, 0);
            acc[2] = __builtin_amdgcn_mfma_f32_32x32x16_bf16(af.bf, bf2.bf, acc[2], 0, 0, 0);
        }
    }

#pragma unroll
    for (int t = 0; t < NTILE; ++t)
#pragma unroll
        for (int r = 0; r < 16; ++r) {
            int brow = (r & 3) + 8 * (r >> 2) + 4 * g;
            partial[((size_t)sc * BATCH + brow) * DIM + dbase + t * 32 + l31] = acc[t][r];
        }
}

// ---------------- K4: merge partials, scale, output ----------------
__global__ __launch_bounds__(256) void k4_final(
        const float* __restrict__ x, const float* __restrict__ partial,
        const float* __restrict__ lsum,
        const float* __restrict__ alphas, const int* __restrict__ tptr,
        float* __restrict__ out) {
    int i = blockIdx.x * 256 + threadIdx.x;
    if (i >= BATCH * DIM) return;
    int b = i / DIM;
    float ab  = alphas[tptr[0]];
    float s   = sqrtf(ab);
    float om  = 1.0f - ab;
    float inv = 1.0f / sqrtf(om);
    float L = 0.0f;
#pragma unroll
    for (int s2 = 0; s2 < 8; ++s2) L += lsum[s2 * 32 + b];
    float wsum = 0.0f;
#pragma unroll 4
    for (int c = 0; c < SCH; ++c)
        wsum += partial[(size_t)c * (BATCH * DIM) + i];
    out[i] = inv * x[i] - s * inv * (wsum / L);
}

extern "C" void kernel_launch(void* const* d_in, const int* in_sizes, int n_in,
                              void* d_out, int out_size, void* d_ws, size_t ws_size,
                              hipStream_t stream) {
    const float* x      = (const float*)d_in[0];
    const float* train  = (const float*)d_in[1];
    const float* alphas = (const float*)d_in[2];
    const int*   tptr   = (const int*)d_in[3];
    float* out = (float*)d_out;

    char* ws = (char*)d_ws;
    float* logits  = (float*)ws;                               // 12,800,000 B
    float* partial = (float*)(ws + 12800000);                  // 38,535,168 B
    u16*   wbuf    = (u16*)(ws + 12800000 + 38535168);         //  6,422,528 B
    float* m_arr   = (float*)(ws + 57757696);                  //        128 B
    float* lsum    = (float*)(ws + 57757824);                  //       1024 B
    u16*   xh      = (u16*)(ws + 57758848);                    //    196,608 B
    u16*   xl      = (u16*)(ws + 57955456);                    //    196,608 B

    k0_split_x<<<(BATCH * DIM + 255) / 256, 256, 0, stream>>>(x, xh, xl);
    k1_logits_v3<<<NTRAIN / 32, 256, 0, stream>>>(train, xh, xl, alphas, tptr, logits);
    k2a_rowmax<<<BATCH, 1024, 0, stream>>>(logits, m_arr);
    k2b_expw<<<256, 256, 0, stream>>>(logits, m_arr, wbuf, lsum);
    k3_pv<<<DSPL * SCH, 256, 0, stream>>>(train, wbuf, partial);
    k4_final<<<(BATCH * DIM + 255) / 256, 256, 0, stream>>>(x, partial, lsum, alphas, tptr, out);
}